// Round 3
// baseline (418.138 us; speedup 1.0000x reference)
//
#include <hip/hip_runtime.h>
#include <hip/hip_cooperative_groups.h>

namespace cg = cooperative_groups;

// Problem constants
#define BATCH 2048
#define FDIM  1024
#define GTILE 16
#define F4    256          // float4 col-groups per row
#define NBLK  256          // one block per CU (co-resident for grid.sync)
#define NTHR  512          // 8 waves per CU
#define RA    8            // rows per block

// ws layout (floats), all fully written before read (poison-safe, no memset):
//   p1  [256][1024] @ 0       : column partial sums of xf          (1 MB)
//   p2s [256][1024] @ 262144  : column partial sums of relu(x-m)   (1 MB)
//   p2q [256][1024] @ 524288  : column partial sumsq               (1 MB)
//   mean[1024]      @ 786432
//   sc  [1024]      @ 787456  : wp / sd
//   cc  [1024]      @ 788480  : mu * sc
#define OFF_P1   0
#define OFF_P2S  262144
#define OFF_P2Q  524288
#define OFF_MEAN 786432
#define OFF_SC   787456
#define OFF_CC   788480

__device__ __forceinline__ void v4add(float4& a, const float4& b) {
    a.x += b.x; a.y += b.y; a.z += b.z; a.w += b.w;
}

__global__ void __launch_bounds__(NTHR) fused_all(const float4* __restrict__ xf,
                                                  const float* __restrict__ wp,
                                                  float* __restrict__ ws,
                                                  float4* __restrict__ out) {
    cg::grid_group grid = cg::this_grid();
    __shared__ float4 ldsa[NTHR];   // 8 KB
    __shared__ float4 ldsb[NTHR];   // 8 KB

    const int t   = threadIdx.x;
    const int b   = blockIdx.x;
    const int cg_ = t & 255;        // col-group 0..255
    const int h   = t >> 8;         // row-half 0/1

    float* p1    = ws + OFF_P1;
    float* p2s   = ws + OFF_P2S;
    float* p2q   = ws + OFF_P2Q;
    float* meanp = ws + OFF_MEAN;
    float* scp   = ws + OFF_SC;
    float* ccp   = ws + OFF_CC;

    // ---------------- P1: column partial sums over this block's 8 rows ----------------
    {
        const float4* xp = xf + (size_t)(b * RA + h) * F4 + cg_;
        float4 s = {0.f, 0.f, 0.f, 0.f};
#pragma unroll
        for (int r = 0; r < 4; ++r) v4add(s, xp[(size_t)(2 * r) * F4]);   // rows h,h+2,h+4,h+6
        ldsa[t] = s;
        __syncthreads();
        if (t < 256) {
            v4add(s, ldsa[t + 256]);
            ((float4*)p1)[b * 256 + t] = s;
        }
    }
    __threadfence();
    grid.sync();

    // ---------------- P2: reduce p1 -> mean (blocks 0,1; coalesced) ----------------
    if (b < 2) {
        const int g = b * NTHR + t;           // column 0..1023
        float s = 0.f;
#pragma unroll 8
        for (int k = 0; k < 256; ++k) s += p1[k * 1024 + g];
        meanp[g] = s * (1.0f / (float)BATCH);
    }
    __threadfence();
    grid.sync();

    // ---------------- P3: relu(x - mean) partial sum / sumsq ----------------
    {
        float4 m = ((const float4*)meanp)[cg_];
        const float4* xp = xf + (size_t)(b * RA + h) * F4 + cg_;
        float4 s = {0.f, 0.f, 0.f, 0.f};
        float4 q = {0.f, 0.f, 0.f, 0.f};
#pragma unroll
        for (int r = 0; r < 4; ++r) {
            float4 v = xp[(size_t)(2 * r) * F4];
            float rx = fmaxf(v.x - m.x, 0.f);
            float ry = fmaxf(v.y - m.y, 0.f);
            float rz = fmaxf(v.z - m.z, 0.f);
            float rw = fmaxf(v.w - m.w, 0.f);
            s.x += rx; s.y += ry; s.z += rz; s.w += rw;
            q.x += rx * rx; q.y += ry * ry; q.z += rz * rz; q.w += rw * rw;
        }
        ldsa[t] = s; ldsb[t] = q;
        __syncthreads();
        if (t < 256) {
            v4add(s, ldsa[t + 256]);
            v4add(q, ldsb[t + 256]);
            ((float4*)p2s)[b * 256 + t] = s;
            ((float4*)p2q)[b * 256 + t] = q;
        }
    }
    __threadfence();
    grid.sync();

    // ---------------- P4: reduce -> scale, cc (blocks 0,1; coalesced) ----------------
    if (b < 2) {
        const int g = b * NTHR + t;
        float S = 0.f, Q = 0.f;
#pragma unroll 8
        for (int k = 0; k < 256; ++k) {
            S += p2s[k * 1024 + g];
            Q += p2q[k * 1024 + g];
        }
        const float w  = wp[0];
        const float mu = S * (1.0f / (float)BATCH);
        const float var = (Q - S * mu) * (1.0f / (float)(BATCH - 1));
        const float scale = w * rsqrtf(var);
        scp[g] = scale;
        ccp[g] = mu * scale;
    }
    __threadfence();
    grid.sync();

    // ---------------- P5: fused normalize + 16-way tiled streaming write ----------------
    {
        float4 m = ((const float4*)meanp)[cg_];
        float4 a = ((const float4*)scp)[cg_];
        float4 c = ((const float4*)ccp)[cg_];
#pragma unroll
        for (int rr = 0; rr < 4; ++rr) {
            const int row = b * RA + h + 2 * rr;
            float4 v = xf[(size_t)row * F4 + cg_];
            float4 o;
            o.x = fmaxf(v.x - m.x, 0.f) * a.x - c.x;
            o.y = fmaxf(v.y - m.y, 0.f) * a.y - c.y;
            o.z = fmaxf(v.z - m.z, 0.f) * a.z - c.z;
            o.w = fmaxf(v.w - m.w, 0.f) * a.w - c.w;
            float4* dst = out + (size_t)row * (GTILE * F4) + cg_;
#pragma unroll
            for (int g2 = 0; g2 < GTILE; ++g2) dst[g2 * F4] = o;
        }
    }
}

extern "C" void kernel_launch(void* const* d_in, const int* in_sizes, int n_in,
                              void* d_out, int out_size, void* d_ws, size_t ws_size,
                              hipStream_t stream) {
    const float4* xf4 = (const float4*)d_in[0];
    const float* wp   = (const float*)d_in[1];
    float* ws         = (float*)d_ws;
    float4* out       = (float4*)d_out;

    void* args[] = { (void*)&xf4, (void*)&wp, (void*)&ws, (void*)&out };
    (void)hipLaunchCooperativeKernel((void*)fused_all, dim3(NBLK), dim3(NTHR),
                                     args, 0, stream);
}

// Round 4
// 158.561 us; speedup vs baseline: 2.6371x; 2.6371x over previous
//
#include <hip/hip_runtime.h>

// Problem constants
#define BATCH 2048
#define FDIM  1024
#define GTILE 16
#define F4    256            // float4 col-groups per row
#define NB1   256            // stats blocks (full chip), 8 rows each
#define RA    8

// ws layout (floats) — every buffer fully written before read (poison-safe):
//   p1  [256][1024] @ 0        column partial sums of xf        (1 MB)
//   p2s [256][1024] @ 262144   column partial sums of relu      (1 MB)
//   p2q [256][1024] @ 524288   column partial sumsq             (1 MB)
//   mean[1024]      @ 786432
//   sc  [1024]      @ 787456   wp / sd
//   cc  [1024]      @ 788480   mu * sc
#define OFF_P1   0
#define OFF_P2S  262144
#define OFF_P2Q  524288
#define OFF_MEAN 786432
#define OFF_SC   787456
#define OFF_CC   788480

typedef float v4f __attribute__((ext_vector_type(4)));

__device__ __forceinline__ void v4add(float4& a, const float4& b) {
    a.x += b.x; a.y += b.y; a.z += b.z; a.w += b.w;
}

// ---- k1: column partial sums, full chip, fully coalesced ----
__global__ void __launch_bounds__(256) k1_colsum(const float4* __restrict__ xf,
                                                 float4* __restrict__ p1) {
    const int cg = threadIdx.x;             // col-group 0..255
    const int b  = blockIdx.x;              // 0..255, 8 rows each
    const float4* p = xf + (size_t)b * RA * F4 + cg;
    float4 s = {0.f, 0.f, 0.f, 0.f};
#pragma unroll
    for (int r = 0; r < RA; ++r) v4add(s, p[r * F4]);
    p1[b * F4 + cg] = s;
}

// ---- k_mean: p1 -> mean. 16 blocks x 256 thr; 4 threads/column, LDS combine ----
__global__ void __launch_bounds__(256) k_mean(const float* __restrict__ p1,
                                              float* __restrict__ mean) {
    __shared__ float sm[256];
    const int t   = threadIdx.x;
    const int b   = blockIdx.x;             // 0..15 -> columns [b*64, b*64+64)
    const int col = b * 64 + (t & 63);
    const int q   = t >> 6;                 // row quarter 0..3
    float s = 0.f;
#pragma unroll 8
    for (int k = 0; k < 64; ++k) s += p1[(q * 64 + k) * FDIM + col];
    sm[t] = s;
    __syncthreads();
    if (t < 64)
        mean[col] = (sm[t] + sm[t + 64] + sm[t + 128] + sm[t + 192]) * (1.0f / (float)BATCH);
}

// ---- k2: relu(x - mean) partial sum/sumsq. mean is a 4 KB L2 broadcast ----
__global__ void __launch_bounds__(256) k2_relustats(const float4* __restrict__ xf,
                                                    const float4* __restrict__ mean4,
                                                    float4* __restrict__ p2s,
                                                    float4* __restrict__ p2q) {
    const int cg = threadIdx.x;
    const int b  = blockIdx.x;
    float4 m = mean4[cg];
    const float4* p = xf + (size_t)b * RA * F4 + cg;
    float4 s = {0.f, 0.f, 0.f, 0.f};
    float4 q = {0.f, 0.f, 0.f, 0.f};
#pragma unroll
    for (int r = 0; r < RA; ++r) {
        float4 v = p[r * F4];
        float rx = fmaxf(v.x - m.x, 0.f);
        float ry = fmaxf(v.y - m.y, 0.f);
        float rz = fmaxf(v.z - m.z, 0.f);
        float rw = fmaxf(v.w - m.w, 0.f);
        s.x += rx; s.y += ry; s.z += rz; s.w += rw;
        q.x += rx * rx; q.y += ry * ry; q.z += rz * rz; q.w += rw * rw;
    }
    p2s[b * F4 + cg] = s;
    p2q[b * F4 + cg] = q;
}

// ---- k3: p2s/p2q -> sc, cc. Same shape as k_mean ----
__global__ void __launch_bounds__(256) k3_scale(const float* __restrict__ wp,
                                                const float* __restrict__ p2s,
                                                const float* __restrict__ p2q,
                                                float* __restrict__ sc,
                                                float* __restrict__ cc) {
    __shared__ float ss[256];
    __shared__ float sq[256];
    const int t   = threadIdx.x;
    const int b   = blockIdx.x;             // 0..15
    const int col = b * 64 + (t & 63);
    const int q   = t >> 6;
    float S = 0.f, Q = 0.f;
#pragma unroll 8
    for (int k = 0; k < 64; ++k) {
        const int r = q * 64 + k;
        S += p2s[r * FDIM + col];
        Q += p2q[r * FDIM + col];
    }
    ss[t] = S; sq[t] = Q;
    __syncthreads();
    if (t < 64) {
        S = ss[t] + ss[t + 64] + ss[t + 128] + ss[t + 192];
        Q = sq[t] + sq[t + 64] + sq[t + 128] + sq[t + 192];
        const float w   = wp[0];
        const float mu  = S * (1.0f / (float)BATCH);
        const float var = (Q - S * mu) * (1.0f / (float)(BATCH - 1));
        const float scale = w * rsqrtf(var);
        sc[col] = scale;
        cc[col] = mu * scale;
    }
}

// ---- k4: fused normalize + 16-way tiled streaming write (non-temporal) ----
__global__ void __launch_bounds__(256) k4_write(const float4* __restrict__ xf,
                                                const float4* __restrict__ mean,
                                                const float4* __restrict__ sc,
                                                const float4* __restrict__ cc,
                                                float4* __restrict__ out) {
    const int tid  = threadIdx.x;           // 0..255
    const int row0 = blockIdx.x * 2;        // 2 rows per block
    float4 v0 = xf[(size_t)row0 * F4 + tid];
    float4 v1 = xf[(size_t)(row0 + 1) * F4 + tid];
    float4 m = mean[tid];
    float4 a = sc[tid];
    float4 c = cc[tid];
    v4f o0, o1;
    o0.x = fmaxf(v0.x - m.x, 0.f) * a.x - c.x;
    o0.y = fmaxf(v0.y - m.y, 0.f) * a.y - c.y;
    o0.z = fmaxf(v0.z - m.z, 0.f) * a.z - c.z;
    o0.w = fmaxf(v0.w - m.w, 0.f) * a.w - c.w;
    o1.x = fmaxf(v1.x - m.x, 0.f) * a.x - c.x;
    o1.y = fmaxf(v1.y - m.y, 0.f) * a.y - c.y;
    o1.z = fmaxf(v1.z - m.z, 0.f) * a.z - c.z;
    o1.w = fmaxf(v1.w - m.w, 0.f) * a.w - c.w;
    v4f* dst0 = (v4f*)(out + (size_t)row0 * (GTILE * F4) + tid);
    v4f* dst1 = dst0 + (GTILE * F4);
#pragma unroll
    for (int g = 0; g < GTILE; ++g) {
        __builtin_nontemporal_store(o0, dst0 + g * F4);
        __builtin_nontemporal_store(o1, dst1 + g * F4);
    }
}

extern "C" void kernel_launch(void* const* d_in, const int* in_sizes, int n_in,
                              void* d_out, int out_size, void* d_ws, size_t ws_size,
                              hipStream_t stream) {
    const float4* xf4 = (const float4*)d_in[0];
    const float* wp   = (const float*)d_in[1];
    float* ws = (float*)d_ws;

    float4* p1   = (float4*)(ws + OFF_P1);
    float4* p2s  = (float4*)(ws + OFF_P2S);
    float4* p2q  = (float4*)(ws + OFF_P2Q);
    float*  mean = ws + OFF_MEAN;
    float*  sc   = ws + OFF_SC;
    float*  cc   = ws + OFF_CC;

    k1_colsum  <<<NB1, 256, 0, stream>>>(xf4, p1);
    k_mean     <<<16,  256, 0, stream>>>((const float*)p1, mean);
    k2_relustats<<<NB1, 256, 0, stream>>>(xf4, (const float4*)mean, p2s, p2q);
    k3_scale   <<<16,  256, 0, stream>>>(wp, (const float*)p2s, (const float*)p2q, sc, cc);
    k4_write   <<<BATCH / 2, 256, 0, stream>>>(xf4, (const float4*)mean,
                                               (const float4*)sc, (const float4*)cc,
                                               (float4*)d_out);
}

// Round 5
// 152.757 us; speedup vs baseline: 2.7373x; 1.0380x over previous
//
#include <hip/hip_runtime.h>

// Problem constants
#define BATCH 2048
#define FDIM  1024
#define GTILE 16
#define F4    256                 // float4 col-groups per row
#define CHUNKS 128
#define RPC   16                  // rows per chunk

// ws layout (floats) — every buffer fully written before read (poison-safe):
//   p1  [128][1024] @ 0        column partial sums of xf        (512 KB)
//   p2s [128][1024] @ 131072   column partial sums of relu      (512 KB)
//   p2q [128][1024] @ 262144   column partial sumsq             (512 KB)
//   mean[1024]      @ 393216
//   sc  [1024]      @ 394240   wp / sd
//   cc  [1024]      @ 395264   mu * sc
#define OFF_P1   0
#define OFF_P2S  131072
#define OFF_P2Q  262144
#define OFF_MEAN 393216
#define OFF_SC   394240
#define OFF_CC   395264

__device__ __forceinline__ void v4add(float4& a, const float4& b) {
    a.x += b.x; a.y += b.y; a.z += b.z; a.w += b.w;
}

// ---- k1: column partial sums. 128 blocks x 512 thr (8 waves/CU on half chip).
// thread (cg, h): sums rows chunk*16 + h + 2r, r=0..7; LDS-combine halves.
__global__ void __launch_bounds__(512) k1_colsum(const float4* __restrict__ xf,
                                                 float4* __restrict__ p1) {
    __shared__ float4 lds[512];     // 8 KB
    const int t  = threadIdx.x;
    const int cg = t & 255;
    const int h  = t >> 8;
    const int b  = blockIdx.x;      // chunk
    const float4* p = xf + (size_t)(b * RPC + h) * F4 + cg;
    float4 s = {0.f, 0.f, 0.f, 0.f};
#pragma unroll
    for (int r = 0; r < 8; ++r) v4add(s, p[(size_t)(2 * r) * F4]);
    lds[t] = s;
    __syncthreads();
    if (t < 256) {
        v4add(s, lds[t + 256]);
        p1[b * F4 + t] = s;
    }
}

// ---- k2: redundant split mean-reduce (64 iters/half + LDS combine), then relu
// partial sum/sumsq over this chunk's 16 rows. Block 0 also stores mean.
__global__ void __launch_bounds__(512) k2_relustats(const float4* __restrict__ xf,
                                                    const float4* __restrict__ p1,
                                                    float4* __restrict__ p2s,
                                                    float4* __restrict__ p2q,
                                                    float4* __restrict__ mean4) {
    __shared__ float4 ldsa[512];    // 8 KB
    __shared__ float4 ldsb[512];    // 8 KB
    const int t  = threadIdx.x;
    const int cg = t & 255;
    const int h  = t >> 8;
    const int b  = blockIdx.x;      // chunk

    // split redundant reduce of p1 -> mean (each half does 64 chunks)
    float4 m = {0.f, 0.f, 0.f, 0.f};
#pragma unroll 8
    for (int c = 0; c < 64; ++c) v4add(m, p1[(h * 64 + c) * F4 + cg]);
    ldsa[t] = m;
    __syncthreads();
    m = ldsa[cg];
    v4add(m, ldsa[cg + 256]);
    const float inv_n = 1.0f / (float)BATCH;
    m.x *= inv_n; m.y *= inv_n; m.z *= inv_n; m.w *= inv_n;
    if (b == 0 && t < 256) mean4[t] = m;

    // relu stats over rows chunk*16 + h + 2r
    const float4* p = xf + (size_t)(b * RPC + h) * F4 + cg;
    float4 s = {0.f, 0.f, 0.f, 0.f};
    float4 q = {0.f, 0.f, 0.f, 0.f};
#pragma unroll
    for (int r = 0; r < 8; ++r) {
        float4 v = p[(size_t)(2 * r) * F4];
        float rx = fmaxf(v.x - m.x, 0.f);
        float ry = fmaxf(v.y - m.y, 0.f);
        float rz = fmaxf(v.z - m.z, 0.f);
        float rw = fmaxf(v.w - m.w, 0.f);
        s.x += rx; s.y += ry; s.z += rz; s.w += rw;
        q.x += rx * rx; q.y += ry * ry; q.z += rz * rz; q.w += rw * rw;
    }
    __syncthreads();                 // ldsa being reused
    ldsa[t] = s; ldsb[t] = q;
    __syncthreads();
    if (t < 256) {
        v4add(s, ldsa[t + 256]);
        v4add(q, ldsb[t + 256]);
        p2s[b * F4 + t] = s;
        p2q[b * F4 + t] = q;
    }
}

// ---- k3: reduce p2s/p2q -> sc, cc. 16 blocks x 256 thr, LDS tree (round-0 proven).
__global__ void __launch_bounds__(256) k3_scale(const float* __restrict__ wp,
                                                const float4* __restrict__ p2s,
                                                const float4* __restrict__ p2q,
                                                float4* __restrict__ sc,
                                                float4* __restrict__ cc) {
    __shared__ float4 rs[256], rq[256];    // 8 KB
    const int t = threadIdx.x;
    const int b = blockIdx.x;              // 0..15
    const int cg = b * 16 + (t & 15);      // col-group
    const int slice = t >> 4;              // 0..15
    const int c0 = slice * (CHUNKS / 16);  // 8 chunks per slice
    float4 s = {0.f,0.f,0.f,0.f}, q = {0.f,0.f,0.f,0.f};
#pragma unroll
    for (int c = c0; c < c0 + CHUNKS / 16; ++c) {
        v4add(s, p2s[c * F4 + cg]);
        v4add(q, p2q[c * F4 + cg]);
    }
    rs[t] = s; rq[t] = q;
    __syncthreads();
    for (int off = 128; off >= 16; off >>= 1) {
        if (t < off) { v4add(rs[t], rs[t + off]); v4add(rq[t], rq[t + off]); }
        __syncthreads();
    }
    if (t < 16) {
        const float inv_n  = 1.0f / (float)BATCH;
        const float inv_n1 = 1.0f / (float)(BATCH - 1);
        const float w = wp[0];
        float4 S = rs[t], Q = rq[t];
        float4 scale, cmb;
        float mu;
        mu = S.x * inv_n; scale.x = w * rsqrtf((Q.x - S.x * mu) * inv_n1); cmb.x = mu * scale.x;
        mu = S.y * inv_n; scale.y = w * rsqrtf((Q.y - S.y * mu) * inv_n1); cmb.y = mu * scale.y;
        mu = S.z * inv_n; scale.z = w * rsqrtf((Q.z - S.z * mu) * inv_n1); cmb.z = mu * scale.z;
        mu = S.w * inv_n; scale.w = w * rsqrtf((Q.w - S.w * mu) * inv_n1); cmb.w = mu * scale.w;
        sc[b * 16 + t] = scale;
        cc[b * 16 + t] = cmb;
    }
}

// ---- k4: fused normalize + 16-way tiled streaming write (round-0 proven). ----
__global__ void __launch_bounds__(256) k4_write(const float4* __restrict__ xf,
                                                const float4* __restrict__ mean,
                                                const float4* __restrict__ sc,
                                                const float4* __restrict__ cc,
                                                float4* __restrict__ out) {
    const int tid  = threadIdx.x;          // 0..255
    const int row0 = blockIdx.x * 2;       // 2 rows per block
    float4 v0 = xf[(size_t)row0 * F4 + tid];
    float4 v1 = xf[(size_t)(row0 + 1) * F4 + tid];
    float4 m = mean[tid];
    float4 a = sc[tid];
    float4 c = cc[tid];
    float4 o0, o1;
    o0.x = fmaxf(v0.x - m.x, 0.f) * a.x - c.x;
    o0.y = fmaxf(v0.y - m.y, 0.f) * a.y - c.y;
    o0.z = fmaxf(v0.z - m.z, 0.f) * a.z - c.z;
    o0.w = fmaxf(v0.w - m.w, 0.f) * a.w - c.w;
    o1.x = fmaxf(v1.x - m.x, 0.f) * a.x - c.x;
    o1.y = fmaxf(v1.y - m.y, 0.f) * a.y - c.y;
    o1.z = fmaxf(v1.z - m.z, 0.f) * a.z - c.z;
    o1.w = fmaxf(v1.w - m.w, 0.f) * a.w - c.w;
    float4* dst0 = out + (size_t)row0 * (GTILE * F4) + tid;
    float4* dst1 = dst0 + (GTILE * F4);
#pragma unroll
    for (int g = 0; g < GTILE; ++g) {
        dst0[g * F4] = o0;
        dst1[g * F4] = o1;
    }
}

extern "C" void kernel_launch(void* const* d_in, const int* in_sizes, int n_in,
                              void* d_out, int out_size, void* d_ws, size_t ws_size,
                              hipStream_t stream) {
    const float4* xf4 = (const float4*)d_in[0];
    const float* wp   = (const float*)d_in[1];
    float* ws = (float*)d_ws;

    float4* p1   = (float4*)(ws + OFF_P1);
    float4* p2s  = (float4*)(ws + OFF_P2S);
    float4* p2q  = (float4*)(ws + OFF_P2Q);
    float4* mean = (float4*)(ws + OFF_MEAN);
    float4* sc   = (float4*)(ws + OFF_SC);
    float4* cc   = (float4*)(ws + OFF_CC);

    k1_colsum   <<<CHUNKS, 512, 0, stream>>>(xf4, p1);
    k2_relustats<<<CHUNKS, 512, 0, stream>>>(xf4, p1, p2s, p2q, mean);
    k3_scale    <<<16,     256, 0, stream>>>(wp, p2s, p2q, sc, cc);
    k4_write    <<<BATCH / 2, 256, 0, stream>>>(xf4, mean, sc, cc, (float4*)d_out);
}